// Round 5
// baseline (355.067 us; speedup 1.0000x reference)
//
#include <hip/hip_runtime.h>

#define HW 3136
#define NB 32
#define NC 128
// Broadcast-row layout: float j at j + 4*(j>>3) (8 data + 4 pad, 48B group
// stride). ds_read_b128 line banks (12g)%32: only g,g+8 alias -> 2-way (free).
#define P4(j) ((j) + ((((j) >> 3)) << 2))

__global__ __launch_bounds__(256, 4)
void mvg_kernel(const float* __restrict__ emb, float* __restrict__ out) {
  // XCD-bijective swizzle (3136 = 8*392): contiguous pos chunk per XCD.
  const int bid = blockIdx.x;
  const int pos = (bid & 7) * 392 + (bid >> 3);
  const int t = threadIdx.x;
  const int rm = t >> 4;
  const int cm = t & 15;
  const int i0 = rm << 3;
  const int c0 = cm << 3;

  __shared__ float Xs[NB * NC];                    // dense 16 KB slice
  __shared__ __align__(16) float bufs[4][192];     // E0,O0,E1,O1 pivot rows
  __shared__ float ms[NC];

  // ---- gather the (B, C) slice ----
  #pragma unroll
  for (int m = 0; m < 16; ++m) {
    const int idx = t + 256 * m;
    const int b = idx >> 7;
    const int c = idx & (NC - 1);
    Xs[idx] = emb[(size_t)b * ((size_t)NC * HW) + (size_t)c * HW + pos];
  }
  __syncthreads();

  // ---- mean over batch, write mean output ----
  if (t < NC) {
    float s = 0.f;
    #pragma unroll
    for (int b = 0; b < NB; ++b) s += Xs[b * NC + t];
    const float m = s * (1.0f / NB);
    ms[t] = m;
    out[(size_t)t * HW + pos] = m;
  }
  __syncthreads();

  // ---- center ----
  #pragma unroll
  for (int m = 0; m < 16; ++m) {
    const int idx = t + 256 * m;
    Xs[idx] -= ms[idx & (NC - 1)];
  }
  __syncthreads();

  float4 a0[8], a1[8];
  #pragma unroll
  for (int r = 0; r < 8; ++r) {
    a0[r] = make_float4(0.f, 0.f, 0.f, 0.f);
    a1[r] = make_float4(0.f, 0.f, 0.f, 0.f);
  }

  #define FMA_TILE(CR, RV0, RV1)                                         \
    _Pragma("unroll")                                                    \
    for (int r = 0; r < 8; ++r) {                                        \
      const float cc = CR[r];                                            \
      a0[r].x = fmaf(cc, RV0.x, a0[r].x);                                \
      a0[r].y = fmaf(cc, RV0.y, a0[r].y);                                \
      a0[r].z = fmaf(cc, RV0.z, a0[r].z);                                \
      a0[r].w = fmaf(cc, RV0.w, a0[r].w);                                \
      a1[r].x = fmaf(cc, RV1.x, a1[r].x);                                \
      a1[r].y = fmaf(cc, RV1.y, a1[r].y);                                \
      a1[r].z = fmaf(cc, RV1.z, a1[r].z);                                \
      a1[r].w = fmaf(cc, RV1.w, a1[r].w);                                \
    }

  // ---- covariance accumulate ----
  for (int b = 0; b < NB; ++b) {
    const float* xr = &Xs[b * NC];
    const float4 rv0 = *(const float4*)&xr[c0];
    const float4 rv1 = *(const float4*)&xr[c0 + 4];
    const float4 cv0 = *(const float4*)&xr[i0];
    const float4 cv1 = *(const float4*)&xr[i0 + 4];
    const float cr[8] = {cv0.x, cv0.y, cv0.z, cv0.w, cv1.x, cv1.y, cv1.z, cv1.w};
    FMA_TILE(cr, rv0, rv1)
  }

  // ---- scale 1/(B-1), + (REG_DIAG+REG_EPS) I ----
  {
    const float s31 = 1.0f / (float)(NB - 1);
    const float RD = 0.01f + 1e-5f;
    #pragma unroll
    for (int r = 0; r < 8; ++r) {
      const int gr = i0 + r;
      a0[r].x = a0[r].x * s31 + ((gr == c0 + 0) ? RD : 0.f);
      a0[r].y = a0[r].y * s31 + ((gr == c0 + 1) ? RD : 0.f);
      a0[r].z = a0[r].z * s31 + ((gr == c0 + 2) ? RD : 0.f);
      a0[r].w = a0[r].w * s31 + ((gr == c0 + 3) ? RD : 0.f);
      a1[r].x = a1[r].x * s31 + ((gr == c0 + 4) ? RD : 0.f);
      a1[r].y = a1[r].y * s31 + ((gr == c0 + 5) ? RD : 0.f);
      a1[r].z = a1[r].z * s31 + ((gr == c0 + 6) ? RD : 0.f);
      a1[r].w = a1[r].w * s31 + ((gr == c0 + 7) ? RD : 0.f);
    }
  }

  // ---- publish rows 0 (E0) and 1 (O0), h-encoded (slot k holds val-1) ----
  if (t < 16) {                       // i0 == 0 owners
    *(float4*)&bufs[0][12 * t] = a0[0];
    *(float4*)&bufs[0][12 * t + 4] = a1[0];
    *(float4*)&bufs[1][12 * t] = a0[1];
    *(float4*)&bufs[1][12 * t + 4] = a1[1];
    if (t == 0) { bufs[0][P4(0)] -= 1.0f; bufs[1][P4(1)] -= 1.0f; }
  }
  __syncthreads();

  // One rank-2 superstep: pivots K0, K0+1 from (EB,OB); owners publish rows
  // K0+2 -> EN, K0+3 -> ON (h-encoded); ONE barrier.
  // h1 = OB - c*EB exactly (h-encoding absorbs the unit-vector terms).
  #define RANK2_STEP(EB, OB, EN, ON, K0) {                                 \
    const float d0m1 = (EB)[P4(K0)];                                       \
    const float vE1  = (EB)[P4((K0) + 1)];                                 \
    const float vO1  = (OB)[P4((K0) + 1)];                                 \
    const float rd0 = __builtin_amdgcn_rcpf(d0m1 + 1.0f);                  \
    const float c_  = vE1 * rd0;                                           \
    const float rd1 = __builtin_amdgcn_rcpf(fmaf(-c_, vE1, vO1) + 1.0f);   \
    const float4 Erv0 = *(const float4*)&(EB)[12 * cm];                    \
    const float4 Erv1 = *(const float4*)&(EB)[12 * cm + 4];                \
    const float4 Ecv0 = *(const float4*)&(EB)[12 * rm];                    \
    const float4 Ecv1 = *(const float4*)&(EB)[12 * rm + 4];                \
    const float nci0[8] = {-(Ecv0.x * rd0), -(Ecv0.y * rd0),               \
                           -(Ecv0.z * rd0), -(Ecv0.w * rd0),               \
                           -(Ecv1.x * rd0), -(Ecv1.y * rd0),               \
                           -(Ecv1.z * rd0), -(Ecv1.w * rd0)};              \
    const float4 Orv0 = *(const float4*)&(OB)[12 * cm];                    \
    const float4 Orv1 = *(const float4*)&(OB)[12 * cm + 4];                \
    const float4 Ocv0 = *(const float4*)&(OB)[12 * rm];                    \
    const float4 Ocv1 = *(const float4*)&(OB)[12 * rm + 4];                \
    float4 Hrv0, Hrv1;                                                     \
    Hrv0.x = fmaf(-c_, Erv0.x, Orv0.x);                                    \
    Hrv0.y = fmaf(-c_, Erv0.y, Orv0.y);                                    \
    Hrv0.z = fmaf(-c_, Erv0.z, Orv0.z);                                    \
    Hrv0.w = fmaf(-c_, Erv0.w, Orv0.w);                                    \
    Hrv1.x = fmaf(-c_, Erv1.x, Orv1.x);                                    \
    Hrv1.y = fmaf(-c_, Erv1.y, Orv1.y);                                    \
    Hrv1.z = fmaf(-c_, Erv1.z, Orv1.z);                                    \
    Hrv1.w = fmaf(-c_, Erv1.w, Orv1.w);                                    \
    const float nci1[8] = {                                                \
      -(fmaf(-c_, Ecv0.x, Ocv0.x) * rd1), -(fmaf(-c_, Ecv0.y, Ocv0.y) * rd1), \
      -(fmaf(-c_, Ecv0.z, Ocv0.z) * rd1), -(fmaf(-c_, Ecv0.w, Ocv0.w) * rd1), \
      -(fmaf(-c_, Ecv1.x, Ocv1.x) * rd1), -(fmaf(-c_, Ecv1.y, Ocv1.y) * rd1), \
      -(fmaf(-c_, Ecv1.z, Ocv1.z) * rd1), -(fmaf(-c_, Ecv1.w, Ocv1.w) * rd1)};\
    FMA_TILE(nci0, Erv0, Erv1)                                             \
    FMA_TILE(nci1, Hrv0, Hrv1)                                             \
    const int kk0 = (K0) + 2;                                              \
    if (kk0 < NC && (unsigned)(kk0 - i0) < 8u) {                           \
      const int lr = kk0 - i0;                                             \
      _Pragma("unroll")                                                    \
      for (int r = 0; r < 8; ++r) {                                        \
        if (r == lr) {                                                     \
          *(float4*)&(EN)[12 * cm] = a0[r];                                \
          *(float4*)&(EN)[12 * cm + 4] = a1[r];                            \
        }                                                                  \
        if (r == lr + 1) {                                                 \
          *(float4*)&(ON)[12 * cm] = a0[r];                                \
          *(float4*)&(ON)[12 * cm + 4] = a1[r];                            \
        }                                                                  \
      }                                                                    \
      if ((unsigned)(kk0 - c0) < 8u) {                                     \
        (EN)[P4(kk0)] -= 1.0f;                                             \
        (ON)[P4(kk0 + 1)] -= 1.0f;                                         \
      }                                                                    \
    }                                                                      \
    __syncthreads();                                                       \
  }

  // ---- 64 rank-2 supersteps (128 pivots), static buffer ping-pong ----
  #pragma unroll 1
  for (int q = 0; q < 32; ++q) {
    const int k0 = q << 2;
    RANK2_STEP(bufs[0], bufs[1], bufs[2], bufs[3], k0)
    RANK2_STEP(bufs[2], bufs[3], bufs[0], bufs[1], k0 + 2)
  }

  // ---- store: inv = -reg, diag = 2 - reg (one +2 artifact per pivot) ----
  float* o = out + (size_t)NC * HW + (size_t)pos * (NC * NC);
  #pragma unroll
  for (int r = 0; r < 8; ++r) {
    const int gr = i0 + r;
    float4 w0, w1;
    w0.x = (gr == c0 + 0) ? (2.0f - a0[r].x) : (-a0[r].x);
    w0.y = (gr == c0 + 1) ? (2.0f - a0[r].y) : (-a0[r].y);
    w0.z = (gr == c0 + 2) ? (2.0f - a0[r].z) : (-a0[r].z);
    w0.w = (gr == c0 + 3) ? (2.0f - a0[r].w) : (-a0[r].w);
    w1.x = (gr == c0 + 4) ? (2.0f - a1[r].x) : (-a1[r].x);
    w1.y = (gr == c0 + 5) ? (2.0f - a1[r].y) : (-a1[r].y);
    w1.z = (gr == c0 + 6) ? (2.0f - a1[r].z) : (-a1[r].z);
    w1.w = (gr == c0 + 7) ? (2.0f - a1[r].w) : (-a1[r].w);
    *(float4*)&o[(size_t)gr * NC + c0] = w0;
    *(float4*)&o[(size_t)gr * NC + c0 + 4] = w1;
  }
}

extern "C" void kernel_launch(void* const* d_in, const int* in_sizes, int n_in,
                              void* d_out, int out_size, void* d_ws, size_t ws_size,
                              hipStream_t stream) {
  const float* emb = (const float*)d_in[0];
  float* out = (float*)d_out;
  mvg_kernel<<<HW, 256, 0, stream>>>(emb, out);
}

// Round 6
// 309.913 us; speedup vs baseline: 1.1457x; 1.1457x over previous
//
#include <hip/hip_runtime.h>

#define HW 3136
#define NB 32
#define NC 128

__global__ __launch_bounds__(256, 4)
void mvg_kernel(const float* __restrict__ emb, float* __restrict__ out) {
  // XCD-bijective swizzle (3136 = 8*392): contiguous pos chunk per XCD.
  const int bid = blockIdx.x;
  const int pos = (bid & 7) * 392 + (bid >> 3);
  const int t = threadIdx.x;
  const int rm = t >> 4;
  const int cm = t & 15;
  const int i0 = rm << 3;
  const int c0 = cm << 3;

  __shared__ float Xs[NB * NC];                  // dense 16 KB slice
  __shared__ __align__(16) float bufA[132];      // pivot row, even steps
  __shared__ __align__(16) float bufB[132];      // pivot row, odd steps
  __shared__ float ms[NC];

  // ---- gather the (B, C) slice ----
  #pragma unroll
  for (int m = 0; m < 16; ++m) {
    const int idx = t + 256 * m;
    const int b = idx >> 7;
    const int c = idx & (NC - 1);
    Xs[idx] = emb[(size_t)b * ((size_t)NC * HW) + (size_t)c * HW + pos];
  }
  __syncthreads();

  // ---- mean over batch, write mean output ----
  if (t < NC) {
    float s = 0.f;
    #pragma unroll
    for (int b = 0; b < NB; ++b) s += Xs[b * NC + t];
    const float m = s * (1.0f / NB);
    ms[t] = m;
    out[(size_t)t * HW + pos] = m;
  }
  __syncthreads();

  // ---- center ----
  #pragma unroll
  for (int m = 0; m < 16; ++m) {
    const int idx = t + 256 * m;
    Xs[idx] -= ms[idx & (NC - 1)];
  }
  __syncthreads();

  float4 a0[8], a1[8];
  #pragma unroll
  for (int r = 0; r < 8; ++r) {
    a0[r] = make_float4(0.f, 0.f, 0.f, 0.f);
    a1[r] = make_float4(0.f, 0.f, 0.f, 0.f);
  }

  #define FMA_TILE(CR, RV0, RV1)                                         \
    _Pragma("unroll")                                                    \
    for (int r = 0; r < 8; ++r) {                                        \
      const float cc = CR[r];                                            \
      a0[r].x = fmaf(cc, RV0.x, a0[r].x);                                \
      a0[r].y = fmaf(cc, RV0.y, a0[r].y);                                \
      a0[r].z = fmaf(cc, RV0.z, a0[r].z);                                \
      a0[r].w = fmaf(cc, RV0.w, a0[r].w);                                \
      a1[r].x = fmaf(cc, RV1.x, a1[r].x);                                \
      a1[r].y = fmaf(cc, RV1.y, a1[r].y);                                \
      a1[r].z = fmaf(cc, RV1.z, a1[r].z);                                \
      a1[r].w = fmaf(cc, RV1.w, a1[r].w);                                \
    }

  // ---- covariance accumulate ----
  for (int b = 0; b < NB; ++b) {
    const float* xr = &Xs[b * NC];
    const float4 rv0 = *(const float4*)&xr[c0];
    const float4 rv1 = *(const float4*)&xr[c0 + 4];
    const float4 cv0 = *(const float4*)&xr[i0];
    const float4 cv1 = *(const float4*)&xr[i0 + 4];
    const float cr[8] = {cv0.x, cv0.y, cv0.z, cv0.w, cv1.x, cv1.y, cv1.z, cv1.w};
    FMA_TILE(cr, rv0, rv1)
  }

  // ---- scale 1/(B-1), + (REG_DIAG+REG_EPS) I ----
  {
    const float s31 = 1.0f / (float)(NB - 1);
    const float RD = 0.01f + 1e-5f;
    #pragma unroll
    for (int r = 0; r < 8; ++r) {
      const int gr = i0 + r;
      a0[r].x = a0[r].x * s31 + ((gr == c0 + 0) ? RD : 0.f);
      a0[r].y = a0[r].y * s31 + ((gr == c0 + 1) ? RD : 0.f);
      a0[r].z = a0[r].z * s31 + ((gr == c0 + 2) ? RD : 0.f);
      a0[r].w = a0[r].w * s31 + ((gr == c0 + 3) ? RD : 0.f);
      a1[r].x = a1[r].x * s31 + ((gr == c0 + 4) ? RD : 0.f);
      a1[r].y = a1[r].y * s31 + ((gr == c0 + 5) ? RD : 0.f);
      a1[r].z = a1[r].z * s31 + ((gr == c0 + 6) ? RD : 0.f);
      a1[r].w = a1[r].w * s31 + ((gr == c0 + 7) ? RD : 0.f);
    }
  }

  // ---- prologue: publish encoded row 0 (slot 0 holds d-1) into bufA ----
  if (rm == 0) {
    float4 t0 = a0[0], t1 = a1[0];
    if (cm == 0) t0.x -= 1.0f;
    *(float4*)&bufA[c0] = t0;
    *(float4*)&bufA[c0 + 4] = t1;
  }
  __syncthreads();

  float4 rvA0 = *(const float4*)&bufA[c0];
  float4 rvA1 = *(const float4*)&bufA[c0 + 4];
  float4 cvA0 = *(const float4*)&bufA[i0];
  float4 cvA1 = *(const float4*)&bufA[i0 + 4];
  float dmA = bufA[0];
  float vkA = bufA[1];
  float4 rvB0, rvB1, cvB0, cvB1;
  float dmB, vkB;

  // One pipelined step for pivot K (data in regs from RB):
  //  1) owner computes row K+1's pivot-K update into temps, publishes to WB
  //     (with the h-encoding -1 at slot K+1) BEFORE the barrier;
  //  2) barrier;
  //  3) prefetch step-K+1 data from WB (latency hidden by 4);
  //  4) bulk rank-1 update of the full tile (includes row K+1 again - the
  //     accumulator copy, which the temps deliberately did not modify).
  #define STEP(RB, WB, K, RV0, RV1, CV0, CV1, DM, VK,                      \
               NRV0, NRV1, NCV0, NCV1, NDM, NVK) {                         \
    const float rd = __builtin_amdgcn_rcpf((DM) + 1.0f);                   \
    const int kk = (K) + 1;                                                \
    if ((unsigned)(kk - i0) < 8u) {                                        \
      const float cok = -(VK) * rd;                                        \
      const int d_ = kk - c0;                                              \
      _Pragma("unroll")                                                    \
      for (int r = 0; r < 8; ++r) if (r == kk - i0) {                      \
        float4 t0, t1;                                                     \
        t0.x = fmaf(cok, RV0.x, a0[r].x) - ((d_ == 0) ? 1.0f : 0.0f);      \
        t0.y = fmaf(cok, RV0.y, a0[r].y) - ((d_ == 1) ? 1.0f : 0.0f);      \
        t0.z = fmaf(cok, RV0.z, a0[r].z) - ((d_ == 2) ? 1.0f : 0.0f);      \
        t0.w = fmaf(cok, RV0.w, a0[r].w) - ((d_ == 3) ? 1.0f : 0.0f);      \
        t1.x = fmaf(cok, RV1.x, a1[r].x) - ((d_ == 4) ? 1.0f : 0.0f);      \
        t1.y = fmaf(cok, RV1.y, a1[r].y) - ((d_ == 5) ? 1.0f : 0.0f);      \
        t1.z = fmaf(cok, RV1.z, a1[r].z) - ((d_ == 6) ? 1.0f : 0.0f);      \
        t1.w = fmaf(cok, RV1.w, a1[r].w) - ((d_ == 7) ? 1.0f : 0.0f);      \
        *(float4*)&(WB)[c0] = t0;                                          \
        *(float4*)&(WB)[c0 + 4] = t1;                                      \
      }                                                                    \
    }                                                                      \
    __syncthreads();                                                       \
    NRV0 = *(const float4*)&(WB)[c0];                                      \
    NRV1 = *(const float4*)&(WB)[c0 + 4];                                  \
    NCV0 = *(const float4*)&(WB)[i0];                                      \
    NCV1 = *(const float4*)&(WB)[i0 + 4];                                  \
    NDM = (WB)[kk];                                                        \
    NVK = (WB)[kk + 1];                                                    \
    const float nci[8] = {-(CV0.x * rd), -(CV0.y * rd), -(CV0.z * rd),     \
                          -(CV0.w * rd), -(CV1.x * rd), -(CV1.y * rd),     \
                          -(CV1.z * rd), -(CV1.w * rd)};                   \
    FMA_TILE(nci, RV0, RV1)                                                \
  }

  // ---- 128 pivots, unrolled x2 with static even/odd buffers ----
  #pragma unroll 1
  for (int q = 0; q < 64; ++q) {
    const int k = q << 1;
    STEP(bufA, bufB, k, rvA0, rvA1, cvA0, cvA1, dmA, vkA,
         rvB0, rvB1, cvB0, cvB1, dmB, vkB)
    STEP(bufB, bufA, k + 1, rvB0, rvB1, cvB0, cvB1, dmB, vkB,
         rvA0, rvA1, cvA0, cvA1, dmA, vkA)
  }

  // ---- store: inv = -reg, diag = 2 - reg (undo the +2 encoding artifact) ----
  float* o = out + (size_t)NC * HW + (size_t)pos * (NC * NC);
  #pragma unroll
  for (int r = 0; r < 8; ++r) {
    const int gr = i0 + r;
    float4 w0, w1;
    w0.x = (gr == c0 + 0) ? (2.0f - a0[r].x) : (-a0[r].x);
    w0.y = (gr == c0 + 1) ? (2.0f - a0[r].y) : (-a0[r].y);
    w0.z = (gr == c0 + 2) ? (2.0f - a0[r].z) : (-a0[r].z);
    w0.w = (gr == c0 + 3) ? (2.0f - a0[r].w) : (-a0[r].w);
    w1.x = (gr == c0 + 4) ? (2.0f - a1[r].x) : (-a1[r].x);
    w1.y = (gr == c0 + 5) ? (2.0f - a1[r].y) : (-a1[r].y);
    w1.z = (gr == c0 + 6) ? (2.0f - a1[r].z) : (-a1[r].z);
    w1.w = (gr == c0 + 7) ? (2.0f - a1[r].w) : (-a1[r].w);
    *(float4*)&o[(size_t)gr * NC + c0] = w0;
    *(float4*)&o[(size_t)gr * NC + c0 + 4] = w1;
  }
}

extern "C" void kernel_launch(void* const* d_in, const int* in_sizes, int n_in,
                              void* d_out, int out_size, void* d_ws, size_t ws_size,
                              hipStream_t stream) {
  const float* emb = (const float*)d_in[0];
  float* out = (float*)d_out;
  mvg_kernel<<<HW, 256, 0, stream>>>(emb, out);
}